// Round 14
// baseline (77.873 us; speedup 1.0000x reference)
//
#include <hip/hip_runtime.h>
#include <math.h>

#define D 256
#define NBATCH 8
#define T 4096
#define M (NBATCH * T)     // 32768
#define LC 64              // chunk length
#define NC (T / LC)        // 64 chunks

typedef __attribute__((ext_vector_type(8))) short bf16x8;
typedef __attribute__((ext_vector_type(4))) float f32x4;

__device__ __forceinline__ unsigned short f2bf(float f) {
    unsigned int u = __float_as_uint(f);
    u += 0x7fff + ((u >> 16) & 1);          // RNE
    return (unsigned short)(u >> 16);
}
__device__ __forceinline__ float bf2f(unsigned short s) {
    return __uint_as_float(((unsigned int)s) << 16);
}

__device__ __forceinline__ void gl_lds16(const unsigned short* g, unsigned short* l) {
    __builtin_amdgcn_global_load_lds(
        (const __attribute__((address_space(1))) unsigned int*)g,
        (__attribute__((address_space(3))) unsigned int*)l, 16, 0, 0);
}

// ---------------- prep: weights + L diagonal in one launch (R9 verbatim) ------
__global__ __launch_bounds__(256) void prep_all(const float* __restrict__ Bre,
                                                const float* __restrict__ Bim,
                                                const float* __restrict__ gamma_log,
                                                const float* __restrict__ Cre,
                                                const float* __restrict__ Cim,
                                                const float* __restrict__ nu_log,
                                                const float* __restrict__ theta_log,
                                                unsigned short* __restrict__ W2,
                                                unsigned short* __restrict__ W3i,
                                                float* __restrict__ Lr,
                                                float* __restrict__ Li) {
    int n = blockIdx.x, k = threadIdx.x;
    if (n < 512) {
        int r = n & 255;
        float g = expf(gamma_log[r]);
        const float* src = (n < 256) ? Bre : Bim;
        W2[(size_t)n * 256 + k] = f2bf(src[(size_t)r * 256 + k] * g);
    } else if (n < 768) {
        int r = n - 512;
        W3i[(size_t)r * 512 + 2 * k]     = f2bf(Cre[(size_t)r * 256 + k]);
        W3i[(size_t)r * 512 + 2 * k + 1] = f2bf(-Cim[(size_t)r * 256 + k]);
    } else {
        float lmod = expf(-expf(nu_log[k]));
        float th = expf(theta_log[k]);
        Lr[k] = lmod * cosf(th);
        Li[k] = lmod * sinf(th);
    }
}

// ---------------- proj GEMM: 64x512 tile, 8 waves (2x4, wave-tile 32x128) -----
// A = x (fp32 -> bf16 reg staging, read ONCE), W = W2 (512x256 B^T). grid (M/64).
// Cols 0-255 -> U4, 256-511 -> V4 (wave-uniform split). t4-interleaved epilogue.
__global__ __launch_bounds__(512) void proj_gemm(const float* __restrict__ x,
                                                 const unsigned short* __restrict__ W,
                                                 unsigned short* __restrict__ U4,
                                                 unsigned short* __restrict__ V4) {
    __shared__ __align__(16) unsigned short As[64 * 32];    // 4 KB
    __shared__ __align__(16) unsigned short Bs[512 * 32];   // 32 KB
    const int tid  = threadIdx.x;
    const int lane = tid & 63;
    const int wid  = tid >> 6;               // 0..7
    const int m0 = blockIdx.x * 64;
    const int wr = wid >> 2, wc = wid & 3;   // 2 x 4 waves, wave-tile 32x128

    f32x4 acc[2][8];
#pragma unroll
    for (int i = 0; i < 2; ++i)
#pragma unroll
        for (int j = 0; j < 8; ++j) acc[i][j] = (f32x4){0.f, 0.f, 0.f, 0.f};

    // A staging (regs, fp32->bf16): thread covers row tid>>3, col quad tid&7
    const int aq = tid & 7, arow = tid >> 3;     // arow 0..63
    const float* gx = x + (size_t)(m0 + arow) * 256 + aq * 4;
    unsigned short* lA = As + arow * 32 + aq * 4;
    // B staging via gl_lds16: wave w stages rows [w*64, w*64+64) (4 calls x 16 rows)
    const int sr = lane >> 2, sc = (lane & 3) * 8;
    const unsigned short* gW = W + (size_t)(wid * 64 + sr) * 256 + sc;
    unsigned short* lB = Bs + wid * 2048;

    const int ar = lane & 15;
    const int ak = (lane >> 4) * 8;

    for (int k0 = 0; k0 < 256; k0 += 32) {
        gl_lds16(gW + k0,                    lB);
        gl_lds16(gW + (size_t)16 * 256 + k0, lB + 512);
        gl_lds16(gW + (size_t)32 * 256 + k0, lB + 1024);
        gl_lds16(gW + (size_t)48 * 256 + k0, lB + 1536);
        {
            float4 v = *(const float4*)(gx + k0);
            union { ushort4 s; unsigned long long u; } o;
            o.s.x = f2bf(v.x); o.s.y = f2bf(v.y); o.s.z = f2bf(v.z); o.s.w = f2bf(v.w);
            *(unsigned long long*)lA = o.u;
        }
        __syncthreads();
        bf16x8 a[2], b[8];
#pragma unroll
        for (int mi = 0; mi < 2; ++mi)
            a[mi] = *(const bf16x8*)(As + (wr * 32 + mi * 16 + ar) * 32 + ak);
#pragma unroll
        for (int ni = 0; ni < 8; ++ni)
            b[ni] = *(const bf16x8*)(Bs + (wc * 128 + ni * 16 + ar) * 32 + ak);
#pragma unroll
        for (int mi = 0; mi < 2; ++mi)
#pragma unroll
            for (int ni = 0; ni < 8; ++ni)
                acc[mi][ni] = __builtin_amdgcn_mfma_f32_16x16x32_bf16(a[mi], b[ni], acc[mi][ni], 0, 0, 0);
        __syncthreads();
    }

    // epilogue: uint2 packed t4-interleaved store (R9 pattern); wc<2 -> U, else V
    const int crow = (lane >> 4) * 4;
    const int ccol = lane & 15;
    unsigned short* base = (wc < 2) ? U4 : V4;
    const int cb = (wc & 1) * 128;
#pragma unroll
    for (int mi = 0; mi < 2; ++mi)
#pragma unroll
        for (int ni = 0; ni < 8; ++ni) {
            const int rg = (m0 + wr * 32 + mi * 16 + crow) >> 2;
            const int c = cb + ni * 16 + ccol;
            uint2 o;
            o.x = (unsigned int)f2bf(acc[mi][ni][0]) | ((unsigned int)f2bf(acc[mi][ni][1]) << 16);
            o.y = (unsigned int)f2bf(acc[mi][ni][2]) | ((unsigned int)f2bf(acc[mi][ni][3]) << 16);
            *(uint2*)(base + ((size_t)rg * 256 + c) * 4) = o;
        }
}

// ---------------- out GEMM: 64x256 tile, 8 waves (2x4, wave-tile 32x64) -------
// A = H (bf16 Mx512, read ONCE), W = W3i (256x512 B^T), fp32 out. grid (M/64).
__global__ __launch_bounds__(512) void out_gemm(const unsigned short* __restrict__ A,
                                                const unsigned short* __restrict__ W,
                                                float* __restrict__ oF) {
    __shared__ __align__(16) unsigned short As[64 * 32];    // 4 KB
    __shared__ __align__(16) unsigned short Bs[256 * 32];   // 16 KB
    const int tid  = threadIdx.x;
    const int lane = tid & 63;
    const int wid  = tid >> 6;               // 0..7
    const int m0 = blockIdx.x * 64;
    const int wr = wid >> 2, wc = wid & 3;   // 2 x 4 waves, wave-tile 32x64

    f32x4 acc[2][4];
#pragma unroll
    for (int i = 0; i < 2; ++i)
#pragma unroll
        for (int j = 0; j < 4; ++j) acc[i][j] = (f32x4){0.f, 0.f, 0.f, 0.f};

    const int sr = lane >> 2;
    const int sc = (lane & 3) * 8;
    // A: waves 0-3 stage rows [w*16, w*16+16) of 64x32 tile (1 call)
    const unsigned short* gA = A + (size_t)(m0 + (wid & 3) * 16 + sr) * 512 + sc;
    unsigned short* lA = As + (wid & 3) * 512;
    // B: wave w stages rows [w*32, w*32+32) of 256x32 tile (2 calls)
    const unsigned short* gW0 = W + (size_t)(wid * 32 + sr) * 512 + sc;
    const unsigned short* gW1 = gW0 + (size_t)16 * 512;
    unsigned short* lB0 = Bs + wid * 1024;
    unsigned short* lB1 = lB0 + 512;

    const int ar = lane & 15;
    const int ak = (lane >> 4) * 8;

    for (int k0 = 0; k0 < 512; k0 += 32) {
        if (wid < 4) gl_lds16(gA + k0, lA);
        gl_lds16(gW0 + k0, lB0);
        gl_lds16(gW1 + k0, lB1);
        __syncthreads();
        bf16x8 a[2], b[4];
#pragma unroll
        for (int mi = 0; mi < 2; ++mi)
            a[mi] = *(const bf16x8*)(As + (wr * 32 + mi * 16 + ar) * 32 + ak);
#pragma unroll
        for (int ni = 0; ni < 4; ++ni)
            b[ni] = *(const bf16x8*)(Bs + (wc * 64 + ni * 16 + ar) * 32 + ak);
#pragma unroll
        for (int mi = 0; mi < 2; ++mi)
#pragma unroll
            for (int ni = 0; ni < 4; ++ni)
                acc[mi][ni] = __builtin_amdgcn_mfma_f32_16x16x32_bf16(a[mi], b[ni], acc[mi][ni], 0, 0, 0);
        __syncthreads();
    }

    const int crow = (lane >> 4) * 4;
    const int ccol = lane & 15;
#pragma unroll
    for (int mi = 0; mi < 2; ++mi)
#pragma unroll
        for (int ni = 0; ni < 4; ++ni) {
            const int r = m0 + wr * 32 + mi * 16 + crow;
            const int c = wc * 64 + ni * 16 + ccol;
#pragma unroll
            for (int j = 0; j < 4; ++j)
                oF[(size_t)(r + j) * 256 + c] = acc[mi][ni][j];
        }
}

// ---------------- scan pass A: chunk-local end states (R9 verbatim) ----------
__global__ __launch_bounds__(256) void scan_ends(const unsigned short* __restrict__ U4,
                                                 const unsigned short* __restrict__ V4,
                                                 const float* __restrict__ Lr,
                                                 const float* __restrict__ Li,
                                                 float* __restrict__ cre, float* __restrict__ cim) {
    int d = threadIdx.x;
    int bc = blockIdx.x;
    float lr = Lr[d], li = Li[d];
    float hr = 0.f, hi = 0.f;
    for (int q = 0; q < 16; ++q) {
        size_t eidx = ((size_t)(bc * 16 + q) * 256 + d) * 4;
        uint2 uu = *(const uint2*)(U4 + eidx);
        uint2 vv = *(const uint2*)(V4 + eidx);
        unsigned int uw[2] = {uu.x, uu.y}, vw[2] = {vv.x, vv.y};
#pragma unroll
        for (int j = 0; j < 4; ++j) {
            float u = bf2f((unsigned short)(uw[j >> 1] >> ((j & 1) * 16)));
            float v = bf2f((unsigned short)(vw[j >> 1] >> ((j & 1) * 16)));
            float nr = fmaf(lr, hr, fmaf(-li, hi, u));
            float ni = fmaf(lr, hi, fmaf(li, hr, v));
            hr = nr; hi = ni;
        }
    }
    cre[(size_t)bc * 256 + d] = hr;
    cim[(size_t)bc * 256 + d] = hi;
}

// ---------------- scan pass B: carries across chunks (R5 verbatim) -----------
__global__ __launch_bounds__(256) void scan_carry(float* __restrict__ cre, float* __restrict__ cim,
                                                  const float* __restrict__ Lr,
                                                  const float* __restrict__ Li) {
    int d = threadIdx.x;
    int b = blockIdx.x;
    float lr = Lr[d], li = Li[d];
    float ar = 1.f, ai = 0.f;
    for (int i = 0; i < LC; i++) {
        float nr = ar * lr - ai * li;
        float ni = ar * li + ai * lr;
        ar = nr; ai = ni;
    }
    float hr = 0.f, hi = 0.f;
    for (int c = 0; c < NC; c++) {
        size_t idx = ((size_t)b * NC + c) * 256 + d;
        float xr = cre[idx], xi = cim[idx];
        cre[idx] = hr;
        cim[idx] = hi;
        float nr = fmaf(ar, hr, fmaf(-ai, hi, xr));
        float ni = fmaf(ar, hi, fmaf(ai, hr, xi));
        hr = nr; hi = ni;
    }
}

// ---------------- scan pass C: full scan with carry-in, H interleaved (R9) ----
__global__ __launch_bounds__(256) void scan_apply(const unsigned short* __restrict__ U4,
                                                  const unsigned short* __restrict__ V4,
                                                  const float* __restrict__ Lr,
                                                  const float* __restrict__ Li,
                                                  const float* __restrict__ cre,
                                                  const float* __restrict__ cim,
                                                  unsigned int* __restrict__ H32) {
    int d = threadIdx.x;
    int bc = blockIdx.x;
    float lr = Lr[d], li = Li[d];
    float hr = cre[(size_t)bc * 256 + d];
    float hi = cim[(size_t)bc * 256 + d];
    for (int q = 0; q < 16; ++q) {
        size_t eidx = ((size_t)(bc * 16 + q) * 256 + d) * 4;
        uint2 uu = *(const uint2*)(U4 + eidx);
        uint2 vv = *(const uint2*)(V4 + eidx);
        unsigned int uw[2] = {uu.x, uu.y}, vw[2] = {vv.x, vv.y};
#pragma unroll
        for (int j = 0; j < 4; ++j) {
            float u = bf2f((unsigned short)(uw[j >> 1] >> ((j & 1) * 16)));
            float v = bf2f((unsigned short)(vw[j >> 1] >> ((j & 1) * 16)));
            float nr = fmaf(lr, hr, fmaf(-li, hi, u));
            float ni = fmaf(lr, hi, fmaf(li, hr, v));
            hr = nr; hi = ni;
            H32[(size_t)(bc * 64 + q * 4 + j) * 256 + d] =
                (unsigned int)f2bf(hr) | ((unsigned int)f2bf(hi) << 16);
        }
    }
}

extern "C" void kernel_launch(void* const* d_in, const int* in_sizes, int n_in,
                              void* d_out, int out_size, void* d_ws, size_t ws_size,
                              hipStream_t stream) {
    const float* x         = (const float*)d_in[0];
    const float* nu_log    = (const float*)d_in[1];
    const float* theta_log = (const float*)d_in[2];
    const float* gamma_log = (const float*)d_in[3];
    const float* B_re      = (const float*)d_in[4];
    const float* B_im      = (const float*)d_in[5];
    const float* C_re      = (const float*)d_in[6];
    const float* C_im      = (const float*)d_in[7];
    float* out = (float*)d_out;

    unsigned short* U4 = (unsigned short*)d_ws;          // M*256 bf16 (16 MB)
    unsigned short* V4 = U4 + (size_t)M * 256;           // 16 MB
    unsigned short* H  = V4 + (size_t)M * 256;           // M*512 bf16 (32 MB)
    unsigned short* W2 = H + (size_t)M * 512;            // 512x256 bf16
    unsigned short* W3i = W2 + (size_t)512 * 256;        // 256x512 bf16
    float* cre = (float*)(W3i + (size_t)256 * 512);      // 512*256 f32
    float* cim = cre + (size_t)NBATCH * NC * 256;
    float* Lr  = cim + (size_t)NBATCH * NC * 256;
    float* Li  = Lr + 256;

    prep_all<<<769, 256, 0, stream>>>(B_re, B_im, gamma_log, C_re, C_im,
                                      nu_log, theta_log, W2, W3i, Lr, Li);
    proj_gemm<<<M / 64, 512, 0, stream>>>(x, W2, U4, V4);
    scan_ends<<<NBATCH * NC, 256, 0, stream>>>(U4, V4, Lr, Li, cre, cim);
    scan_carry<<<NBATCH, 256, 0, stream>>>(cre, cim, Lr, Li);
    scan_apply<<<NBATCH * NC, 256, 0, stream>>>(U4, V4, Lr, Li, cre, cim,
                                                (unsigned int*)H);
    out_gemm<<<M / 64, 512, 0, stream>>>(H, W3i, out);
}

// Round 15
// 66.610 us; speedup vs baseline: 1.1691x; 1.1691x over previous
//
#include <hip/hip_runtime.h>
#include <math.h>

#define D 256
#define NBATCH 8
#define T 4096
#define M (NBATCH * T)     // 32768
#define LC 64              // chunk length
#define NC (T / LC)        // 64 chunks

typedef __attribute__((ext_vector_type(8))) short bf16x8;
typedef __attribute__((ext_vector_type(4))) float f32x4;

__device__ __forceinline__ unsigned short f2bf(float f) {
    unsigned int u = __float_as_uint(f);
    u += 0x7fff + ((u >> 16) & 1);          // RNE
    return (unsigned short)(u >> 16);
}
__device__ __forceinline__ float bf2f(unsigned short s) {
    return __uint_as_float(((unsigned int)s) << 16);
}

__device__ __forceinline__ void gl_lds16(const unsigned short* g, unsigned short* l) {
    __builtin_amdgcn_global_load_lds(
        (const __attribute__((address_space(1))) unsigned int*)g,
        (__attribute__((address_space(3))) unsigned int*)l, 16, 0, 0);
}

// ---------------- prep: weights + L diagonal in one launch ----------------
__global__ __launch_bounds__(256) void prep_all(const float* __restrict__ Bre,
                                                const float* __restrict__ Bim,
                                                const float* __restrict__ gamma_log,
                                                const float* __restrict__ Cre,
                                                const float* __restrict__ Cim,
                                                const float* __restrict__ nu_log,
                                                const float* __restrict__ theta_log,
                                                unsigned short* __restrict__ W2,
                                                unsigned short* __restrict__ W3i,
                                                float* __restrict__ Lr,
                                                float* __restrict__ Li) {
    int n = blockIdx.x, k = threadIdx.x;
    if (n < 512) {
        int r = n & 255;
        float g = expf(gamma_log[r]);
        const float* src = (n < 256) ? Bre : Bim;
        W2[(size_t)n * 256 + k] = f2bf(src[(size_t)r * 256 + k] * g);
    } else if (n < 768) {
        int r = n - 512;
        W3i[(size_t)r * 512 + 2 * k]     = f2bf(Cre[(size_t)r * 256 + k]);
        W3i[(size_t)r * 512 + 2 * k + 1] = f2bf(-Cim[(size_t)r * 256 + k]);
    } else {
        float lmod = expf(-expf(nu_log[k]));
        float th = expf(theta_log[k]);
        Lr[k] = lmod * cosf(th);
        Li[k] = lmod * sinf(th);
    }
}

// ---------------- proj GEMM: 128x256 tile, 8 waves (2x4), BK=32 ---------------
__global__ __launch_bounds__(512) void proj_gemm(const float* __restrict__ x,
                                                 const unsigned short* __restrict__ W,
                                                 unsigned short* __restrict__ U4,
                                                 unsigned short* __restrict__ V4) {
    __shared__ __align__(16) unsigned short As[128 * 32];   // 8 KB
    __shared__ __align__(16) unsigned short Bs[256 * 32];   // 16 KB
    const int tid  = threadIdx.x;
    const int lane = tid & 63;
    const int wid  = tid >> 6;          // 0..7
    const int m0 = blockIdx.x * 128;
    const int n0 = blockIdx.y * 256;    // 0 or 256 (row offset into W2)
    const int wr = wid >> 2, wc = wid & 3;   // 2 x 4 waves, 64x64 tiles

    f32x4 acc[4][4];
#pragma unroll
    for (int i = 0; i < 4; ++i)
#pragma unroll
        for (int j = 0; j < 4; ++j) acc[i][j] = (f32x4){0.f, 0.f, 0.f, 0.f};

    const int aq = tid & 7, arow = tid >> 3;            // arow 0..63
    const float* gx = x + (size_t)(m0 + arow) * 256 + aq * 4;
    unsigned short* lA = As + arow * 32 + aq * 4;
    const int sr = lane >> 2, sc = (lane & 3) * 8;
    const unsigned short* gW0 = W + (size_t)(n0 + wid * 32 + sr) * 256 + sc;
    const unsigned short* gW1 = gW0 + (size_t)16 * 256;
    unsigned short* lB0 = Bs + wid * 1024;
    unsigned short* lB1 = lB0 + 512;

    const int ar = lane & 15;
    const int ak = (lane >> 4) * 8;

    for (int k0 = 0; k0 < 256; k0 += 32) {
        gl_lds16(gW0 + k0, lB0);
        gl_lds16(gW1 + k0, lB1);
#pragma unroll
        for (int i = 0; i < 2; ++i) {
            float4 v = *(const float4*)(gx + (size_t)(64 * i) * 256 + k0);
            union { ushort4 s; unsigned long long u; } o;
            o.s.x = f2bf(v.x); o.s.y = f2bf(v.y); o.s.z = f2bf(v.z); o.s.w = f2bf(v.w);
            *(unsigned long long*)(lA + (size_t)i * 64 * 32) = o.u;
        }
        __syncthreads();
        bf16x8 a[4], b[4];
#pragma unroll
        for (int mi = 0; mi < 4; ++mi)
            a[mi] = *(const bf16x8*)(As + (wr * 64 + mi * 16 + ar) * 32 + ak);
#pragma unroll
        for (int ni = 0; ni < 4; ++ni)
            b[ni] = *(const bf16x8*)(Bs + (wc * 64 + ni * 16 + ar) * 32 + ak);
#pragma unroll
        for (int mi = 0; mi < 4; ++mi)
#pragma unroll
            for (int ni = 0; ni < 4; ++ni)
                acc[mi][ni] = __builtin_amdgcn_mfma_f32_16x16x32_bf16(a[mi], b[ni], acc[mi][ni], 0, 0, 0);
        __syncthreads();
    }

    const int crow = (lane >> 4) * 4;
    const int ccol = lane & 15;
    unsigned short* base = (n0 == 0) ? U4 : V4;
#pragma unroll
    for (int mi = 0; mi < 4; ++mi)
#pragma unroll
        for (int ni = 0; ni < 4; ++ni) {
            const int rg = (m0 + wr * 64 + mi * 16 + crow) >> 2;
            const int c = wc * 64 + ni * 16 + ccol;
            uint2 o;
            o.x = (unsigned int)f2bf(acc[mi][ni][0]) | ((unsigned int)f2bf(acc[mi][ni][1]) << 16);
            o.y = (unsigned int)f2bf(acc[mi][ni][2]) | ((unsigned int)f2bf(acc[mi][ni][3]) << 16);
            *(uint2*)(base + ((size_t)rg * 256 + c) * 4) = o;
        }
}

// ---------------- out GEMM: 128x128 tile, 8 waves (4x2, wave-tile 32x64) ------
__global__ __launch_bounds__(512) void out_gemm(const unsigned short* __restrict__ A,
                                                const unsigned short* __restrict__ W,
                                                float* __restrict__ oF) {
    __shared__ __align__(16) unsigned short As[128 * 32];   // 8 KB
    __shared__ __align__(16) unsigned short Bs[128 * 32];   // 8 KB
    const int tid  = threadIdx.x;
    const int lane = tid & 63;
    const int wid  = tid >> 6;          // 0..7
    const int m0 = blockIdx.x * 128;
    const int n0 = blockIdx.y * 128;
    const int wr = wid >> 1, wc = wid & 1;   // 4 x 2 waves, wave-tile 32x64

    f32x4 acc[2][4];
#pragma unroll
    for (int i = 0; i < 2; ++i)
#pragma unroll
        for (int j = 0; j < 4; ++j) acc[i][j] = (f32x4){0.f, 0.f, 0.f, 0.f};

    const int sr = lane >> 2;           // 0..15
    const int sc = (lane & 3) * 8;
    const unsigned short* gA0 = A + (size_t)(m0 + wid * 16 + sr) * 512 + sc;
    const unsigned short* gW0 = W + (size_t)(n0 + wid * 16 + sr) * 512 + sc;
    unsigned short* lA0 = As + wid * 512;
    unsigned short* lB0 = Bs + wid * 512;

    const int ar = lane & 15;
    const int ak = (lane >> 4) * 8;

    for (int k0 = 0; k0 < 512; k0 += 32) {
        gl_lds16(gA0 + k0, lA0);
        gl_lds16(gW0 + k0, lB0);
        __syncthreads();
        bf16x8 a[2], b[4];
#pragma unroll
        for (int mi = 0; mi < 2; ++mi)
            a[mi] = *(const bf16x8*)(As + (wr * 32 + mi * 16 + ar) * 32 + ak);
#pragma unroll
        for (int ni = 0; ni < 4; ++ni)
            b[ni] = *(const bf16x8*)(Bs + (wc * 64 + ni * 16 + ar) * 32 + ak);
#pragma unroll
        for (int mi = 0; mi < 2; ++mi)
#pragma unroll
            for (int ni = 0; ni < 4; ++ni)
                acc[mi][ni] = __builtin_amdgcn_mfma_f32_16x16x32_bf16(a[mi], b[ni], acc[mi][ni], 0, 0, 0);
        __syncthreads();
    }

    const int crow = (lane >> 4) * 4;
    const int ccol = lane & 15;
#pragma unroll
    for (int mi = 0; mi < 2; ++mi)
#pragma unroll
        for (int ni = 0; ni < 4; ++ni) {
            const int r = m0 + wr * 32 + mi * 16 + crow;
            const int c = n0 + wc * 64 + ni * 16 + ccol;
#pragma unroll
            for (int j = 0; j < 4; ++j)
                oF[(size_t)(r + j) * 256 + c] = acc[mi][ni][j];
        }
}

// ---------------- scan pass A: chunk-local end states ----------
__global__ __launch_bounds__(256) void scan_ends(const unsigned short* __restrict__ U4,
                                                 const unsigned short* __restrict__ V4,
                                                 const float* __restrict__ Lr,
                                                 const float* __restrict__ Li,
                                                 float* __restrict__ cre, float* __restrict__ cim) {
    int d = threadIdx.x;
    int bc = blockIdx.x;
    float lr = Lr[d], li = Li[d];
    float hr = 0.f, hi = 0.f;
    for (int q = 0; q < 16; ++q) {
        size_t eidx = ((size_t)(bc * 16 + q) * 256 + d) * 4;
        uint2 uu = *(const uint2*)(U4 + eidx);
        uint2 vv = *(const uint2*)(V4 + eidx);
        unsigned int uw[2] = {uu.x, uu.y}, vw[2] = {vv.x, vv.y};
#pragma unroll
        for (int j = 0; j < 4; ++j) {
            float u = bf2f((unsigned short)(uw[j >> 1] >> ((j & 1) * 16)));
            float v = bf2f((unsigned short)(vw[j >> 1] >> ((j & 1) * 16)));
            float nr = fmaf(lr, hr, fmaf(-li, hi, u));
            float ni = fmaf(lr, hi, fmaf(li, hr, v));
            hr = nr; hi = ni;
        }
    }
    cre[(size_t)bc * 256 + d] = hr;
    cim[(size_t)bc * 256 + d] = hi;
}

// ---------------- scan pass B: carries across chunks (exclusive) -----------
__global__ __launch_bounds__(256) void scan_carry(float* __restrict__ cre, float* __restrict__ cim,
                                                  const float* __restrict__ Lr,
                                                  const float* __restrict__ Li) {
    int d = threadIdx.x;
    int b = blockIdx.x;
    float lr = Lr[d], li = Li[d];
    float ar = 1.f, ai = 0.f;
    for (int i = 0; i < LC; i++) {
        float nr = ar * lr - ai * li;
        float ni = ar * li + ai * lr;
        ar = nr; ai = ni;
    }
    float hr = 0.f, hi = 0.f;
    for (int c = 0; c < NC; c++) {
        size_t idx = ((size_t)b * NC + c) * 256 + d;
        float xr = cre[idx], xi = cim[idx];
        cre[idx] = hr;
        cim[idx] = hi;
        float nr = fmaf(ar, hr, fmaf(-ai, hi, xr));
        float ni = fmaf(ar, hi, fmaf(ai, hr, xi));
        hr = nr; hi = ni;
    }
}

// ---------------- scan pass C: full scan with carry-in, H interleaved ----
__global__ __launch_bounds__(256) void scan_apply(const unsigned short* __restrict__ U4,
                                                  const unsigned short* __restrict__ V4,
                                                  const float* __restrict__ Lr,
                                                  const float* __restrict__ Li,
                                                  const float* __restrict__ cre,
                                                  const float* __restrict__ cim,
                                                  unsigned int* __restrict__ H32) {
    int d = threadIdx.x;
    int bc = blockIdx.x;
    float lr = Lr[d], li = Li[d];
    float hr = cre[(size_t)bc * 256 + d];
    float hi = cim[(size_t)bc * 256 + d];
    for (int q = 0; q < 16; ++q) {
        size_t eidx = ((size_t)(bc * 16 + q) * 256 + d) * 4;
        uint2 uu = *(const uint2*)(U4 + eidx);
        uint2 vv = *(const uint2*)(V4 + eidx);
        unsigned int uw[2] = {uu.x, uu.y}, vw[2] = {vv.x, vv.y};
#pragma unroll
        for (int j = 0; j < 4; ++j) {
            float u = bf2f((unsigned short)(uw[j >> 1] >> ((j & 1) * 16)));
            float v = bf2f((unsigned short)(vw[j >> 1] >> ((j & 1) * 16)));
            float nr = fmaf(lr, hr, fmaf(-li, hi, u));
            float ni = fmaf(lr, hi, fmaf(li, hr, v));
            hr = nr; hi = ni;
            H32[(size_t)(bc * 64 + q * 4 + j) * 256 + d] =
                (unsigned int)f2bf(hr) | ((unsigned int)f2bf(hi) << 16);
        }
    }
}

extern "C" void kernel_launch(void* const* d_in, const int* in_sizes, int n_in,
                              void* d_out, int out_size, void* d_ws, size_t ws_size,
                              hipStream_t stream) {
    const float* x         = (const float*)d_in[0];
    const float* nu_log    = (const float*)d_in[1];
    const float* theta_log = (const float*)d_in[2];
    const float* gamma_log = (const float*)d_in[3];
    const float* B_re      = (const float*)d_in[4];
    const float* B_im      = (const float*)d_in[5];
    const float* C_re      = (const float*)d_in[6];
    const float* C_im      = (const float*)d_in[7];
    float* out = (float*)d_out;

    unsigned short* U4 = (unsigned short*)d_ws;          // M*256 bf16 (16 MB)
    unsigned short* V4 = U4 + (size_t)M * 256;           // 16 MB
    unsigned short* H  = V4 + (size_t)M * 256;           // M*512 bf16 (32 MB)
    unsigned short* W2 = H + (size_t)M * 512;            // 512x256 bf16
    unsigned short* W3i = W2 + (size_t)512 * 256;        // 256x512 bf16
    float* cre = (float*)(W3i + (size_t)256 * 512);      // 512*256 f32
    float* cim = cre + (size_t)NBATCH * NC * 256;
    float* Lr  = cim + (size_t)NBATCH * NC * 256;
    float* Li  = Lr + 256;

    prep_all<<<769, 256, 0, stream>>>(B_re, B_im, gamma_log, C_re, C_im,
                                      nu_log, theta_log, W2, W3i, Lr, Li);
    proj_gemm<<<dim3(M / 128, 2), 512, 0, stream>>>(x, W2, U4, V4);
    scan_ends<<<NBATCH * NC, 256, 0, stream>>>(U4, V4, Lr, Li, cre, cim);
    scan_carry<<<NBATCH, 256, 0, stream>>>(cre, cim, Lr, Li);
    scan_apply<<<NBATCH * NC, 256, 0, stream>>>(U4, V4, Lr, Li, cre, cim,
                                                (unsigned int*)H);
    out_gemm<<<dim3(M / 128, 2), 512, 0, stream>>>(H, W3i, out);
}